// Round 5
// baseline (201.697 us; speedup 1.0000x reference)
//
#include <hip/hip_runtime.h>

typedef unsigned short u16;
typedef unsigned int u32;

typedef __attribute__((ext_vector_type(4))) float f32x4;
typedef __attribute__((ext_vector_type(8))) short s16x8;
typedef __attribute__((ext_vector_type(4))) short s16x4;

__device__ __forceinline__ u16 f2bf(float f) {
    u32 u = __builtin_bit_cast(u32, f);
    u += 0x7fffu + ((u >> 16) & 1u);
    return (u16)(u >> 16);
}

__device__ __forceinline__ u32 pk_bf16(float a, float b) {
    return (u32)f2bf(a) | ((u32)f2bf(b) << 16);
}

// HW packed f32x2 -> bf16x2 (RNE), 1 instr
__device__ __forceinline__ u32 cvtpk(float a, float b) {
    u32 r;
    asm("v_cvt_pk_bf16_f32 %0, %1, %2" : "=v"(r) : "v"(a), "v"(b));
    return r;
}

#define EXP2(x) exp2f(x)

// async global -> LDS, 16B per lane; LDS dest = wave-uniform base + lane*16
__device__ __forceinline__ void gload16(const u16* g, u16* l) {
    __builtin_amdgcn_global_load_lds(
        (const __attribute__((address_space(1))) void*)(const void*)g,
        (__attribute__((address_space(3))) void*)(void*)l, 16, 0, 0);
}

// ---------------- cast x: f32 -> bf16, 4 elems/thread ----------------
__global__ void k_cast(const float* __restrict__ in, u16* __restrict__ out) {
    int i = (blockIdx.x * 256 + threadIdx.x) * 4;
    float4 v = *(const float4*)(in + i);
    uint2 pk;
    pk.x = pk_bf16(v.x, v.y);
    pk.y = pk_bf16(v.z, v.w);
    *(uint2*)(out + i) = pk;
}

// ------- transpose+cast weights: in [K][N] f32 -> out [N][K] bf16 -------
__global__ void k_transpose(const float* __restrict__ in, u16* __restrict__ out,
                            int K, int N) {
    __shared__ float tile[32][33];
    int n0 = blockIdx.x * 32, k0 = blockIdx.y * 32;
    int x = threadIdx.x, y = threadIdx.y;  // block (32,8)
#pragma unroll
    for (int j = 0; j < 32; j += 8)
        tile[y + j][x] = in[(size_t)(k0 + y + j) * N + n0 + x];
    __syncthreads();
#pragma unroll
    for (int j = 0; j < 32; j += 8)
        out[(size_t)(n0 + y + j) * K + k0 + x] = f2bf(tile[x][y + j]);
}

// ---------------- GEMM (m97 pattern): C[M,N] = A[M,K] @ Bt[N,K]^T --------
template <int EPI>
__global__ __launch_bounds__(256, 2) void k_gemm(
        const u16* __restrict__ A, const u16* __restrict__ Bt,
        void* __restrict__ Cout, u16* __restrict__ Vt, int N, int K) {
    __shared__ u16 As[128 * 32];
    __shared__ u16 Bs[128 * 32];
    const int nbn = N >> 7;
    const int bm = (int)blockIdx.x / nbn, bn = (int)blockIdx.x % nbn;
    const int tid = threadIdx.x;
    const int wv = tid >> 6, ln = tid & 63;
    const int lg = ln >> 4, lr = ln & 15;
    const int wr = (wv >> 1) << 6, wc = (wv & 1) << 6;

    const u16* gA = A + (size_t)(bm * 128 + wv * 32 + (ln >> 2)) * K + (ln & 3) * 8;
    const u16* gB = Bt + (size_t)(bn * 128 + wv * 32 + (ln >> 2)) * K + (ln & 3) * 8;
    u16* lA = As + wv * 1024;
    u16* lB = Bs + wv * 1024;

    f32x4 acc[4][4] = {};

    for (int k0 = 0; k0 < K; k0 += 32) {
        gload16(gA + k0, lA);
        gload16(gA + k0 + 16 * K, lA + 512);
        gload16(gB + k0, lB);
        gload16(gB + k0 + 16 * K, lB + 512);
        __syncthreads();
        s16x8 af[4], bf[4];
#pragma unroll
        for (int mi = 0; mi < 4; ++mi)
            af[mi] = *(const s16x8*)&As[(wr + mi * 16 + lr) * 32 + lg * 8];
#pragma unroll
        for (int ni = 0; ni < 4; ++ni)
            bf[ni] = *(const s16x8*)&Bs[(wc + ni * 16 + lr) * 32 + lg * 8];
#pragma unroll
        for (int mi = 0; mi < 4; ++mi)
#pragma unroll
            for (int ni = 0; ni < 4; ++ni)
                acc[mi][ni] = __builtin_amdgcn_mfma_f32_16x16x32_bf16(
                        af[mi], bf[ni], acc[mi][ni], 0, 0, 0);
        __syncthreads();
    }

    const int crow0 = bm * 128 + wr + lg * 4;
    const int ccol0 = bn * 128 + wc + lr;
    if (EPI == 0) {
        float* Co = (float*)Cout;
#pragma unroll
        for (int mi = 0; mi < 4; ++mi)
#pragma unroll
            for (int ni = 0; ni < 4; ++ni)
#pragma unroll
                for (int r = 0; r < 4; ++r)
                    Co[(size_t)(crow0 + mi * 16 + r) * N + ccol0 + ni * 16] =
                            acc[mi][ni][r];
    } else {
        if (bn < 16) {  // K and Q thirds; Q pre-scaled by 0.125*log2(e)
            const float qs = (bn >= 8) ? 0.18033688011112042f : 1.0f;
            u16* Co = (u16*)Cout;
#pragma unroll
            for (int mi = 0; mi < 4; ++mi)
#pragma unroll
                for (int ni = 0; ni < 4; ++ni)
#pragma unroll
                    for (int r = 0; r < 4; ++r)
                        Co[(size_t)(crow0 + mi * 16 + r) * 3072 + ccol0 + ni * 16] =
                                f2bf(acc[mi][ni][r] * qs);
        } else {  // V third -> Vt[(b*1024 + hd)][t]
#pragma unroll
            for (int mi = 0; mi < 4; ++mi) {
                int row = crow0 + mi * 16;
                int bb = row >> 11, t = row & 2047;
#pragma unroll
                for (int ni = 0; ni < 4; ++ni) {
                    int hd = ccol0 + ni * 16 - 2048;
                    uint2 pk;
                    pk.x = pk_bf16(acc[mi][ni][0], acc[mi][ni][1]);
                    pk.y = pk_bf16(acc[mi][ni][2], acc[mi][ni][3]);
                    *(uint2*)&Vt[(size_t)(bb * 1024 + hd) * 2048 + t] = pk;
                }
            }
        }
    }
}

// ---------------- causal flash attention (swapped QK^T, 2-phase) --------
// 1024 blocks, one 64-row q-tile each; XCD swizzle keeps a (b,h)'s K/V on
// one XCD's L2; qt order big/small interleaved for CU load balance.
// K/V staged by global_load_lds into XOR-swizzled linear LDS (chunk^=row&7),
// double-buffered, ONE asm{vmcnt(0);s_barrier} per tile (T3-lite).
// P in per-wave LDS with 8B-granule rotation -> conflict-free b64 W/R.
// No online softmax (Q pre-scaled to log2 units); l via ones-MFMA.
__global__ __launch_bounds__(256, 4) void k_attn(
        const u16* __restrict__ kqv, const u16* __restrict__ Vt,
        u16* __restrict__ y) {
    const int orig = blockIdx.x;
    const int xcd = orig & 7, slot = orig >> 3;   // HW: block i -> XCD i%8
    const int bh = xcd * 4 + (slot >> 5);
    const int qs = slot & 31;
    const int qt = (qs & 1) ? (31 - (qs >> 1)) : (qs >> 1);
    const int b = bh >> 4, h = bh & 15;
    const int tid = threadIdx.x;
    const int wave = tid >> 6, lane = tid & 63;
    const int lg = lane >> 4, lr = lane & 15;

    __shared__ u16 Ks[2][64 * 64];   // [buf][k-row][d], chunk-swizzled
    __shared__ u16 Vs[2][64 * 64];   // [buf][d][t],     chunk-swizzled
    __shared__ u16 Ps[4][16 * 64];   // per-wave P, 8B-slot rotated

    const u16* Kg = kqv + (size_t)b * 2048 * 3072 + h * 64;
    const u16* Qg = Kg + 1024;
    const u16* Vg = Vt + (size_t)bh * 64 * 2048;

    // staging geometry: issue j covers rows wave*16 + j*8 + (lane>>3);
    // lane writes LDS slot (lane&7); data chunk c = slot ^ (row&7).
    const int srow = wave * 16 + (lane >> 3);
    const int cK = (lane & 7) ^ (lane >> 3);
    const u16* kg0 = Kg + (size_t)srow * 3072 + cK * 8;
    const u16* vg0 = Vg + (size_t)srow * 2048 + cK * 8;

    const int nkt = qt + 1;
    const int qbase = qt * 64 + wave * 16;

    // Q fragments (B-operand: row q = lr, d = lg*8..+7), pre-scaled
    const u16* qrp = Qg + (size_t)(qbase + lr) * 3072;
    const s16x8 qf0 = *(const s16x8*)(qrp + lg * 8);
    const s16x8 qf1 = *(const s16x8*)(qrp + 32 + lg * 8);

    s16x8 ones;
#pragma unroll
    for (int i = 0; i < 8; ++i) ones[i] = (short)0x3F80;  // bf16 1.0

    f32x4 o[4] = {};   // O^T frags: d = dt*16+lg*4+r, q = lr
    f32x4 l4 = {};     // row-sum accumulator

    u16* Psw = &Ps[wave][0];
    const int swz = (lr & 7);  // read-side chunk XOR

#define STAGE(bb, t)                                            \
    {                                                           \
        const u16* kp_ = kg0 + (size_t)(t) * 64 * 3072;         \
        const u16* vp_ = vg0 + (size_t)(t) * 64;                \
        u16* lk_ = &Ks[bb][wave * 1024];                        \
        u16* lv_ = &Vs[bb][wave * 1024];                        \
        gload16(kp_, lk_);                                      \
        gload16(kp_ + 8 * 3072, lk_ + 512);                     \
        gload16(vp_, lv_);                                      \
        gload16(vp_ + 8 * 2048, lv_ + 512);                     \
    }

    // prologue: stage tile 0
    STAGE(0, 0);
    asm volatile("s_waitcnt vmcnt(0)\n\ts_barrier" ::: "memory");

    for (int kt = 0; kt < nkt; ++kt) {
        const int cur = kt & 1;
        if (kt + 1 < nkt) STAGE(cur ^ 1, kt + 1);  // flies under compute

        // S^T[k][q] = mfma(K-frag, Q-frag); lane: k = kb*16+lg*4+r, q = lr
        f32x4 st[4];
        __builtin_amdgcn_s_setprio(1);
#pragma unroll
        for (int kb = 0; kb < 4; ++kb) {
            const int row = kb * 16 + lr;
            s16x8 kf0 = *(const s16x8*)&Ks[cur][row * 64 + ((lg ^ swz) << 3)];
            s16x8 kf1 = *(const s16x8*)&Ks[cur][row * 64 + (((4 + lg) ^ swz) << 3)];
            f32x4 z = {};
            z = __builtin_amdgcn_mfma_f32_16x16x32_bf16(kf0, qf0, z, 0, 0, 0);
            z = __builtin_amdgcn_mfma_f32_16x16x32_bf16(kf1, qf1, z, 0, 0, 0);
            st[kb] = z;
        }
        __builtin_amdgcn_s_setprio(0);

        // p = exp2(st); causal mask only on the diagonal tile
        if (kt == nkt - 1) {
            const int q_abs = qbase + lr;
            const int kb0 = kt * 64 + lg * 4;
#pragma unroll
            for (int kb = 0; kb < 4; ++kb)
#pragma unroll
                for (int r = 0; r < 4; ++r)
                    st[kb][r] = EXP2((kb0 + kb * 16 + r <= q_abs)
                                         ? st[kb][r] : -3e38f);
        } else {
#pragma unroll
            for (int kb = 0; kb < 4; ++kb)
#pragma unroll
                for (int r = 0; r < 4; ++r) st[kb][r] = EXP2(st[kb][r]);
        }

        // P -> per-wave LDS: block-of-4 k-elems (8B) at slot (kblk4+lr)&15
        // -> 16 lanes hit 16 distinct bank-pairs: conflict-free
#pragma unroll
        for (int kb = 0; kb < 4; ++kb) {
            const int sw = (kb * 4 + lg + lr) & 15;
            uint2 w;
            w.x = cvtpk(st[kb][0], st[kb][1]);
            w.y = cvtpk(st[kb][2], st[kb][3]);
            *(uint2*)&Psw[lr * 64 + sw * 4] = w;
        }
        asm volatile("s_waitcnt lgkmcnt(0)" ::: "memory");
        __builtin_amdgcn_sched_barrier(0);

        // O^T += mfma(V^T-frag, P-frag);  l += mfma(ones, P-frag)
        __builtin_amdgcn_s_setprio(1);
#pragma unroll
        for (int half = 0; half < 2; ++half) {
            const int s0 = (half * 8 + lg * 2 + lr) & 15;
            const int s1 = (half * 8 + lg * 2 + 1 + lr) & 15;
            s16x4 pa = *(const s16x4*)&Psw[lr * 64 + s0 * 4];
            s16x4 pb = *(const s16x4*)&Psw[lr * 64 + s1 * 4];
            s16x8 pf = __builtin_shufflevector(pa, pb, 0, 1, 2, 3, 4, 5, 6, 7);
            l4 = __builtin_amdgcn_mfma_f32_16x16x32_bf16(ones, pf, l4, 0, 0, 0);
#pragma unroll
            for (int dt = 0; dt < 4; ++dt) {
                const int vrow = dt * 16 + lr;
                s16x8 vf = *(const s16x8*)&Vs[cur][vrow * 64 +
                                                   (((half * 4 + lg) ^ swz) << 3)];
                o[dt] = __builtin_amdgcn_mfma_f32_16x16x32_bf16(vf, pf, o[dt], 0, 0, 0);
            }
        }
        __builtin_amdgcn_s_setprio(0);

        // next tile staged & everyone done reading cur
        asm volatile("s_waitcnt vmcnt(0)\n\ts_barrier" ::: "memory");
    }
#undef STAGE

    // normalize + write y[b*2048+q][h*64+d]; lane: q=qbase+lr, d=dt*16+lg*4+r
    const float inv = 1.0f / l4[0];
    u16* yb = y + (size_t)(b * 2048 + qbase + lr) * 1024 + h * 64;
#pragma unroll
    for (int dt = 0; dt < 4; ++dt) {
        uint2 w;
        w.x = cvtpk(o[dt][0] * inv, o[dt][1] * inv);
        w.y = cvtpk(o[dt][2] * inv, o[dt][3] * inv);
        *(uint2*)(yb + dt * 16 + lg * 4) = w;
    }
}

extern "C" void kernel_launch(void* const* d_in, const int* in_sizes, int n_in,
                              void* d_out, int out_size, void* d_ws, size_t ws_size,
                              hipStream_t stream) {
    const float* x = (const float*)d_in[0];
    const float* w_attn = (const float*)d_in[1];
    const float* w_proj = (const float*)d_in[2];
    float* out = (float*)d_out;
    char* ws = (char*)d_ws;

    u16* x_bf = (u16*)(ws);                        // 8 MB   [4096,1024]
    u16* wat  = (u16*)(ws + (size_t)(8 << 20));    // 6 MB   [3072,1024] = w_attn^T
    u16* wpt  = (u16*)(ws + (size_t)(14 << 20));   // 2 MB   [1024,1024] = w_proj^T
    u16* kqv  = (u16*)(ws + (size_t)(16 << 20));   // 24 MB  [4096,3072] (K,Q thirds)
    u16* vt   = (u16*)(ws + (size_t)(40 << 20));   // 8 MB   [B*H*D, T]
    u16* yb   = (u16*)(ws + (size_t)(48 << 20));   // 8 MB   [4096,1024]

    k_cast<<<4096, 256, 0, stream>>>(x, x_bf);
    k_transpose<<<dim3(96, 32), dim3(32, 8), 0, stream>>>(w_attn, wat, 1024, 3072);
    k_transpose<<<dim3(32, 32), dim3(32, 8), 0, stream>>>(w_proj, wpt, 1024, 1024);
    k_gemm<1><<<32 * 24, 256, 0, stream>>>(x_bf, wat, kqv, vt, 3072, 1024);
    k_attn<<<1024, 256, 0, stream>>>(kqv, vt, yb);
    k_gemm<0><<<32 * 8, 256, 0, stream>>>(yb, wpt, out, nullptr, 1024, 1024);
}

// Round 6
// 179.162 us; speedup vs baseline: 1.1258x; 1.1258x over previous
//
#include <hip/hip_runtime.h>

typedef unsigned short u16;
typedef unsigned int u32;

typedef __attribute__((ext_vector_type(4))) float f32x4;
typedef __attribute__((ext_vector_type(8))) short s16x8;

__device__ __forceinline__ u16 f2bf(float f) {
    u32 u = __builtin_bit_cast(u32, f);
    u += 0x7fffu + ((u >> 16) & 1u);
    return (u16)(u >> 16);
}

__device__ __forceinline__ u32 pk_bf16(float a, float b) {
    return (u32)f2bf(a) | ((u32)f2bf(b) << 16);
}

// HW packed f32x2 -> bf16x2 (RNE), 1 instr
__device__ __forceinline__ u32 cvtpk(float a, float b) {
    u32 r;
    asm("v_cvt_pk_bf16_f32 %0, %1, %2" : "=v"(r) : "v"(a), "v"(b));
    return r;
}

__device__ __forceinline__ float bf2f(u16 h) {
    u32 u = ((u32)h) << 16;
    return __builtin_bit_cast(float, u);
}

#define EXP2(x) exp2f(x)

// async global -> LDS, 16B per lane; LDS dest = wave-uniform base + lane*16
__device__ __forceinline__ void gload16(const u16* g, u16* l) {
    __builtin_amdgcn_global_load_lds(
        (const __attribute__((address_space(1))) void*)(const void*)g,
        (__attribute__((address_space(3))) void*)(void*)l, 16, 0, 0);
}

// ---------------- cast x: f32 -> bf16, 4 elems/thread ----------------
__global__ void k_cast(const float* __restrict__ in, u16* __restrict__ out) {
    int i = (blockIdx.x * 256 + threadIdx.x) * 4;
    float4 v = *(const float4*)(in + i);
    uint2 pk;
    pk.x = pk_bf16(v.x, v.y);
    pk.y = pk_bf16(v.z, v.w);
    *(uint2*)(out + i) = pk;
}

// ------- transpose+cast weights: in [K][N] f32 -> out [N][K] bf16 -------
__global__ void k_transpose(const float* __restrict__ in, u16* __restrict__ out,
                            int K, int N) {
    __shared__ float tile[32][33];
    int n0 = blockIdx.x * 32, k0 = blockIdx.y * 32;
    int x = threadIdx.x, y = threadIdx.y;  // block (32,8)
#pragma unroll
    for (int j = 0; j < 32; j += 8)
        tile[y + j][x] = in[(size_t)(k0 + y + j) * N + n0 + x];
    __syncthreads();
#pragma unroll
    for (int j = 0; j < 32; j += 8)
        out[(size_t)(n0 + y + j) * K + k0 + x] = f2bf(tile[x][y + j]);
}

// ---------------- GEMM (m97 pattern): C[M,N] = A[M,K] @ Bt[N,K]^T --------
template <int EPI>
__global__ __launch_bounds__(256, 2) void k_gemm(
        const u16* __restrict__ A, const u16* __restrict__ Bt,
        void* __restrict__ Cout, u16* __restrict__ Vt, int N, int K) {
    __shared__ u16 As[128 * 32];
    __shared__ u16 Bs[128 * 32];
    const int nbn = N >> 7;
    const int bm = (int)blockIdx.x / nbn, bn = (int)blockIdx.x % nbn;
    const int tid = threadIdx.x;
    const int wv = tid >> 6, ln = tid & 63;
    const int lg = ln >> 4, lr = ln & 15;
    const int wr = (wv >> 1) << 6, wc = (wv & 1) << 6;

    const u16* gA = A + (size_t)(bm * 128 + wv * 32 + (ln >> 2)) * K + (ln & 3) * 8;
    const u16* gB = Bt + (size_t)(bn * 128 + wv * 32 + (ln >> 2)) * K + (ln & 3) * 8;
    u16* lA = As + wv * 1024;
    u16* lB = Bs + wv * 1024;

    f32x4 acc[4][4] = {};

    for (int k0 = 0; k0 < K; k0 += 32) {
        gload16(gA + k0, lA);
        gload16(gA + k0 + 16 * K, lA + 512);
        gload16(gB + k0, lB);
        gload16(gB + k0 + 16 * K, lB + 512);
        __syncthreads();
        s16x8 af[4], bf[4];
#pragma unroll
        for (int mi = 0; mi < 4; ++mi)
            af[mi] = *(const s16x8*)&As[(wr + mi * 16 + lr) * 32 + lg * 8];
#pragma unroll
        for (int ni = 0; ni < 4; ++ni)
            bf[ni] = *(const s16x8*)&Bs[(wc + ni * 16 + lr) * 32 + lg * 8];
#pragma unroll
        for (int mi = 0; mi < 4; ++mi)
#pragma unroll
            for (int ni = 0; ni < 4; ++ni)
                acc[mi][ni] = __builtin_amdgcn_mfma_f32_16x16x32_bf16(
                        af[mi], bf[ni], acc[mi][ni], 0, 0, 0);
        __syncthreads();
    }

    const int crow0 = bm * 128 + wr + lg * 4;
    const int ccol0 = bn * 128 + wc + lr;
    if (EPI == 0) {
        float* Co = (float*)Cout;
#pragma unroll
        for (int mi = 0; mi < 4; ++mi)
#pragma unroll
            for (int ni = 0; ni < 4; ++ni)
#pragma unroll
                for (int r = 0; r < 4; ++r)
                    Co[(size_t)(crow0 + mi * 16 + r) * N + ccol0 + ni * 16] =
                            acc[mi][ni][r];
    } else {
        if (bn < 16) {  // K and Q thirds; Q pre-scaled by 0.125*log2(e)
            const float qs = (bn >= 8) ? 0.18033688011112042f : 1.0f;
            u16* Co = (u16*)Cout;
#pragma unroll
            for (int mi = 0; mi < 4; ++mi)
#pragma unroll
                for (int ni = 0; ni < 4; ++ni)
#pragma unroll
                    for (int r = 0; r < 4; ++r)
                        Co[(size_t)(crow0 + mi * 16 + r) * 3072 + ccol0 + ni * 16] =
                                f2bf(acc[mi][ni][r] * qs);
        } else {  // V third -> Vt[(b*1024 + hd)][t]
#pragma unroll
            for (int mi = 0; mi < 4; ++mi) {
                int row = crow0 + mi * 16;
                int bb = row >> 11, t = row & 2047;
#pragma unroll
                for (int ni = 0; ni < 4; ++ni) {
                    int hd = ccol0 + ni * 16 - 2048;
                    uint2 pk;
                    pk.x = pk_bf16(acc[mi][ni][0], acc[mi][ni][1]);
                    pk.y = pk_bf16(acc[mi][ni][2], acc[mi][ni][3]);
                    *(uint2*)&Vt[(size_t)(bb * 1024 + hd) * 2048 + t] = pk;
                }
            }
        }
    }
}

// -------- causal flash attention: swapped QK^T + split-K in block --------
// 512 blocks x 512 threads.  Block = (bh, pair pr): passes qt=pr, 31-pr
// (assignment-immune load balance: every block's critical path = 17 tiles).
// 8 waves = 2 k-parity groups x 4 waves; group g handles k-tiles t%2==g with
// its OWN double-buffered K/V LDS -> groups never wait on each other's loads,
// 4 waves/SIMD latency hiding.  No-max exp2 softmax is linear, so partial
// (o,l) just add: group1 passes its partials through LDS (bf16 o, f32 l).
// K/V staged by global_load_lds, XOR-swizzled (chunk^=row&7), one
// vmcnt(0)+barrier per tile.  l via ones-MFMA; Q pre-scaled to log2 units.
__global__ __launch_bounds__(512, 4) void k_attn(
        const u16* __restrict__ kqv, const u16* __restrict__ Vt,
        u16* __restrict__ y) {
    const int orig = blockIdx.x;
    const int xcd = orig & 7, slot = orig >> 3;   // HW: block i -> XCD i%8
    const int bh = xcd * 4 + (slot >> 4);
    const int pr = slot & 15;
    const int b = bh >> 4, h = bh & 15;
    const int tid = threadIdx.x;
    const int wave = tid >> 6;      // 0..7
    const int g = wave >> 2;        // k-parity group
    const int wv4 = wave & 3;
    const int lane = tid & 63;
    const int lg = lane >> 4, lr = lane & 15;

    __shared__ u16 Ks[2][2][64 * 64];  // [group][buf][krow*64+d] swizzled
    __shared__ u16 Vs[2][2][64 * 64];  // [group][buf][d*64+t]    swizzled
    __shared__ u16 Ps[8][16 * 64];     // per-wave P (16B-slot rotated)
    u16* comb = &Ps[0][0];             // aliases Ps after tile loops:
                                       // entry stride 20 u16 = 4x uint2 + f32

    const u16* Kg = kqv + (size_t)b * 2048 * 3072 + h * 64;
    const u16* Qg = Kg + 1024;
    const u16* Vg = Vt + (size_t)bh * 64 * 2048;

    // staging: wave covers rows wv4*16 + (lane>>3) (+8 on 2nd issue);
    // lane's LDS slot = lane&7, so global chunk = slot ^ (row&7)
    const int srow = wv4 * 16 + (lane >> 3);
    const int cK = (lane & 7) ^ (lane >> 3);
    const u16* kg0 = Kg + (size_t)srow * 3072 + cK * 8;
    const u16* vg0 = Vg + (size_t)srow * 2048 + cK * 8;
    const int swz = lr & 7;  // read-side chunk XOR (row&7 == lr&7)

    s16x8 ones;
#pragma unroll
    for (int i = 0; i < 8; ++i) ones[i] = (short)0x3F80;  // bf16 1.0

    u16* Psw = &Ps[wave][0];

#define STAGE(bb, t)                                      \
    {                                                     \
        const u16* kp_ = kg0 + (size_t)(t) * 64 * 3072;   \
        const u16* vp_ = vg0 + (size_t)(t) * 64;          \
        u16* lk_ = &Ks[g][bb][wv4 * 1024];                \
        u16* lv_ = &Vs[g][bb][wv4 * 1024];                \
        gload16(kp_, lk_);                                \
        gload16(kp_ + 8 * 3072, lk_ + 512);               \
        gload16(vp_, lv_);                                \
        gload16(vp_ + 8 * 2048, lv_ + 512);               \
    }

    for (int pass = 0; pass < 2; ++pass) {
        const int qt = pass ? (31 - pr) : pr;
        const int nkt = qt + 1;
        const int iters = (nkt + 1) >> 1;   // group0 tile count (>= group1's)
        const int qbase = qt * 64 + wv4 * 16;

        // Q fragments (B-operand: q = lr, d = lg*8..+7), pre-scaled
        const u16* qrp = Qg + (size_t)(qbase + lr) * 3072;
        const s16x8 qf0 = *(const s16x8*)(qrp + lg * 8);
        const s16x8 qf1 = *(const s16x8*)(qrp + 32 + lg * 8);

        f32x4 o[4] = {};  // O^T frags: d = dt*16+lg*4+r, q = lr
        f32x4 l4 = {};    // row-sum (every elem equals the row sum)

        if (g < nkt) STAGE(0, g);
        asm volatile("s_waitcnt vmcnt(0)\n\ts_barrier" ::: "memory");

        for (int i = 0; i < iters; ++i) {
            const int cur = i & 1;
            const int t = 2 * i + g;
            if (t + 2 < nkt) STAGE(cur ^ 1, t + 2);  // flies under compute
            if (t < nkt) {
                // S^T[k][q] = mfma(K,Q); lane: k = kb*16+lg*4+r, q = lr
                f32x4 st[4];
                __builtin_amdgcn_s_setprio(1);
#pragma unroll
                for (int kb = 0; kb < 4; ++kb) {
                    const int row = kb * 16 + lr;
                    s16x8 kf0 = *(const s16x8*)&Ks[g][cur][row * 64 + ((lg ^ swz) << 3)];
                    s16x8 kf1 = *(const s16x8*)&Ks[g][cur][row * 64 + (((4 + lg) ^ swz) << 3)];
                    f32x4 z = {};
                    z = __builtin_amdgcn_mfma_f32_16x16x32_bf16(kf0, qf0, z, 0, 0, 0);
                    z = __builtin_amdgcn_mfma_f32_16x16x32_bf16(kf1, qf1, z, 0, 0, 0);
                    st[kb] = z;
                }
                __builtin_amdgcn_s_setprio(0);

                // p = exp2(st); causal mask only on the diagonal tile
                if (t == nkt - 1) {
                    const int q_abs = qbase + lr;
                    const int kb0 = t * 64 + lg * 4;
#pragma unroll
                    for (int kb = 0; kb < 4; ++kb)
#pragma unroll
                        for (int r = 0; r < 4; ++r)
                            st[kb][r] = EXP2((kb0 + kb * 16 + r <= q_abs)
                                                 ? st[kb][r] : -3e38f);
                } else {
#pragma unroll
                    for (int kb = 0; kb < 4; ++kb)
#pragma unroll
                        for (int r = 0; r < 4; ++r) st[kb][r] = EXP2(st[kb][r]);
                }

                // P -> per-wave LDS (16B-slot rotation)
#pragma unroll
                for (int kb = 0; kb < 4; ++kb) {
                    const int kbs = (kb + lr) & 3;
                    uint2 w;
                    w.x = cvtpk(st[kb][0], st[kb][1]);
                    w.y = cvtpk(st[kb][2], st[kb][3]);
                    *(uint2*)&Psw[lr * 64 + kbs * 16 + lg * 4] = w;
                }
                asm volatile("s_waitcnt lgkmcnt(0)" ::: "memory");
                __builtin_amdgcn_sched_barrier(0);

                // O^T += mfma(V^T, P);  l += mfma(ones, P)
                __builtin_amdgcn_s_setprio(1);
#pragma unroll
                for (int half = 0; half < 2; ++half) {
                    const int kbs = ((half * 2 + (lg >> 1)) + lr) & 3;
                    s16x8 pf = *(const s16x8*)&Psw[lr * 64 + kbs * 16 + (lg & 1) * 8];
                    l4 = __builtin_amdgcn_mfma_f32_16x16x32_bf16(ones, pf, l4, 0, 0, 0);
#pragma unroll
                    for (int dt = 0; dt < 4; ++dt) {
                        const int vrow = dt * 16 + lr;
                        s16x8 vf = *(const s16x8*)&Vs[g][cur][vrow * 64 +
                                                    (((half * 4 + lg) ^ swz) << 3)];
                        o[dt] = __builtin_amdgcn_mfma_f32_16x16x32_bf16(vf, pf, o[dt], 0, 0, 0);
                    }
                }
                __builtin_amdgcn_s_setprio(0);
            }
            // next tile staged & this group's reads of cur done
            asm volatile("s_waitcnt vmcnt(0)\n\ts_barrier" ::: "memory");
        }

        // ---- combine group partials: y = (o0 + o1) / (l0 + l1) ----
        __syncthreads();  // all Ps reads done; comb may alias Ps
        if (g == 1) {
            u16* ce = comb + (size_t)(wv4 * 64 + lane) * 20;
#pragma unroll
            for (int dt = 0; dt < 4; ++dt) {
                uint2 w;
                w.x = cvtpk(o[dt][0], o[dt][1]);
                w.y = cvtpk(o[dt][2], o[dt][3]);
                *(uint2*)(ce + dt * 4) = w;
            }
            *(float*)(ce + 16) = l4[0];
        }
        __syncthreads();
        if (g == 0) {
            const u16* ce = comb + (size_t)(wv4 * 64 + lane) * 20;
            float l = l4[0] + *(const float*)(ce + 16);
#pragma unroll
            for (int dt = 0; dt < 4; ++dt) {
                uint2 w = *(const uint2*)(ce + dt * 4);
                o[dt][0] += bf2f((u16)(w.x & 0xffff));
                o[dt][1] += bf2f((u16)(w.x >> 16));
                o[dt][2] += bf2f((u16)(w.y & 0xffff));
                o[dt][3] += bf2f((u16)(w.y >> 16));
            }
            const float inv = 1.0f / l;
            u16* yb = y + (size_t)(b * 2048 + qbase + lr) * 1024 + h * 64;
#pragma unroll
            for (int dt = 0; dt < 4; ++dt) {
                uint2 w;
                w.x = cvtpk(o[dt][0] * inv, o[dt][1] * inv);
                w.y = cvtpk(o[dt][2] * inv, o[dt][3] * inv);
                *(uint2*)(yb + dt * 16 + lg * 4) = w;
            }
        }
        __syncthreads();  // comb reads done before next pass's Ps writes
    }
#undef STAGE
}

extern "C" void kernel_launch(void* const* d_in, const int* in_sizes, int n_in,
                              void* d_out, int out_size, void* d_ws, size_t ws_size,
                              hipStream_t stream) {
    const float* x = (const float*)d_in[0];
    const float* w_attn = (const float*)d_in[1];
    const float* w_proj = (const float*)d_in[2];
    float* out = (float*)d_out;
    char* ws = (char*)d_ws;

    u16* x_bf = (u16*)(ws);                        // 8 MB   [4096,1024]
    u16* wat  = (u16*)(ws + (size_t)(8 << 20));    // 6 MB   [3072,1024] = w_attn^T
    u16* wpt  = (u16*)(ws + (size_t)(14 << 20));   // 2 MB   [1024,1024] = w_proj^T
    u16* kqv  = (u16*)(ws + (size_t)(16 << 20));   // 24 MB  [4096,3072] (K,Q thirds)
    u16* vt   = (u16*)(ws + (size_t)(40 << 20));   // 8 MB   [B*H*D, T]
    u16* yb   = (u16*)(ws + (size_t)(48 << 20));   // 8 MB   [4096,1024]

    k_cast<<<4096, 256, 0, stream>>>(x, x_bf);
    k_transpose<<<dim3(96, 32), dim3(32, 8), 0, stream>>>(w_attn, wat, 1024, 3072);
    k_transpose<<<dim3(32, 32), dim3(32, 8), 0, stream>>>(w_proj, wpt, 1024, 1024);
    k_gemm<1><<<32 * 24, 256, 0, stream>>>(x_bf, wat, kqv, vt, 3072, 1024);
    k_attn<<<512, 512, 0, stream>>>(kqv, vt, yb);
    k_gemm<0><<<32 * 8, 256, 0, stream>>>(yb, wpt, out, nullptr, 1024, 1024);
}

// Round 7
// 172.037 us; speedup vs baseline: 1.1724x; 1.0414x over previous
//
#include <hip/hip_runtime.h>

typedef unsigned short u16;
typedef unsigned int u32;

typedef __attribute__((ext_vector_type(4))) float f32x4;
typedef __attribute__((ext_vector_type(8))) short s16x8;
typedef __attribute__((ext_vector_type(4))) u32 u32x4;

__device__ __forceinline__ u16 f2bf(float f) {
    u32 u = __builtin_bit_cast(u32, f);
    u += 0x7fffu + ((u >> 16) & 1u);
    return (u16)(u >> 16);
}

__device__ __forceinline__ u32 pk_bf16(float a, float b) {
    return (u32)f2bf(a) | ((u32)f2bf(b) << 16);
}

// HW packed f32x2 -> bf16x2 (RNE), 1 instr
__device__ __forceinline__ u32 cvtpk(float a, float b) {
    u32 r;
    asm("v_cvt_pk_bf16_f32 %0, %1, %2" : "=v"(r) : "v"(a), "v"(b));
    return r;
}

__device__ __forceinline__ float bf2f(u16 h) {
    u32 u = ((u32)h) << 16;
    return __builtin_bit_cast(float, u);
}

// gfx950 cross-lane swaps (VALU pipe, both operands updated):
// 32: a.rows2-3 (lanes>=32) <-> b.rows0-1 ; 16: a.rows1,3 <-> b.rows0,2
__device__ __forceinline__ void pl32swap(u32& a, u32& b) {
    asm volatile("v_permlane32_swap_b32 %0, %1" : "+v"(a), "+v"(b));
}
__device__ __forceinline__ void pl16swap(u32& a, u32& b) {
    asm volatile("v_permlane16_swap_b32 %0, %1" : "+v"(a), "+v"(b));
}

#define EXP2(x) exp2f(x)

// async global -> LDS, 16B per lane; LDS dest = wave-uniform base + lane*16
__device__ __forceinline__ void gload16(const u16* g, u16* l) {
    __builtin_amdgcn_global_load_lds(
        (const __attribute__((address_space(1))) void*)(const void*)g,
        (__attribute__((address_space(3))) void*)(void*)l, 16, 0, 0);
}

// ---------------- cast x: f32 -> bf16, 4 elems/thread ----------------
__global__ void k_cast(const float* __restrict__ in, u16* __restrict__ out) {
    int i = (blockIdx.x * 256 + threadIdx.x) * 4;
    float4 v = *(const float4*)(in + i);
    uint2 pk;
    pk.x = pk_bf16(v.x, v.y);
    pk.y = pk_bf16(v.z, v.w);
    *(uint2*)(out + i) = pk;
}

// ------- transpose+cast weights: in [K][N] f32 -> out [N][K] bf16 -------
__global__ void k_transpose(const float* __restrict__ in, u16* __restrict__ out,
                            int K, int N) {
    __shared__ float tile[32][33];
    int n0 = blockIdx.x * 32, k0 = blockIdx.y * 32;
    int x = threadIdx.x, y = threadIdx.y;  // block (32,8)
#pragma unroll
    for (int j = 0; j < 32; j += 8)
        tile[y + j][x] = in[(size_t)(k0 + y + j) * N + n0 + x];
    __syncthreads();
#pragma unroll
    for (int j = 0; j < 32; j += 8)
        out[(size_t)(n0 + y + j) * K + k0 + x] = f2bf(tile[x][y + j]);
}

// ---------------- GEMM (m97 pattern): C[M,N] = A[M,K] @ Bt[N,K]^T --------
// XCD-bijective block swizzle (nwg % 8 == 0 for both instantiations).
template <int EPI>
__global__ __launch_bounds__(256, 2) void k_gemm(
        const u16* __restrict__ A, const u16* __restrict__ Bt,
        void* __restrict__ Cout, u16* __restrict__ Vt, int N, int K) {
    __shared__ u16 As[128 * 32];
    __shared__ u16 Bs[128 * 32];
    const int nbn = N >> 7;
    const int cpx = (int)gridDim.x >> 3;
    const int bid = (int)blockIdx.x;
    const int swb = (bid & 7) * cpx + (bid >> 3);
    const int bm = swb / nbn, bn = swb % nbn;
    const int tid = threadIdx.x;
    const int wv = tid >> 6, ln = tid & 63;
    const int lg = ln >> 4, lr = ln & 15;
    const int wr = (wv >> 1) << 6, wc = (wv & 1) << 6;

    const u16* gA = A + (size_t)(bm * 128 + wv * 32 + (ln >> 2)) * K + (ln & 3) * 8;
    const u16* gB = Bt + (size_t)(bn * 128 + wv * 32 + (ln >> 2)) * K + (ln & 3) * 8;
    u16* lA = As + wv * 1024;
    u16* lB = Bs + wv * 1024;

    f32x4 acc[4][4] = {};

    for (int k0 = 0; k0 < K; k0 += 32) {
        gload16(gA + k0, lA);
        gload16(gA + k0 + 16 * K, lA + 512);
        gload16(gB + k0, lB);
        gload16(gB + k0 + 16 * K, lB + 512);
        __syncthreads();
        s16x8 af[4], bf[4];
#pragma unroll
        for (int mi = 0; mi < 4; ++mi)
            af[mi] = *(const s16x8*)&As[(wr + mi * 16 + lr) * 32 + lg * 8];
#pragma unroll
        for (int ni = 0; ni < 4; ++ni)
            bf[ni] = *(const s16x8*)&Bs[(wc + ni * 16 + lr) * 32 + lg * 8];
#pragma unroll
        for (int mi = 0; mi < 4; ++mi)
#pragma unroll
            for (int ni = 0; ni < 4; ++ni)
                acc[mi][ni] = __builtin_amdgcn_mfma_f32_16x16x32_bf16(
                        af[mi], bf[ni], acc[mi][ni], 0, 0, 0);
        __syncthreads();
    }

    const int crow0 = bm * 128 + wr + lg * 4;
    const int ccol0 = bn * 128 + wc + lr;
    if (EPI == 0) {
        float* Co = (float*)Cout;
#pragma unroll
        for (int mi = 0; mi < 4; ++mi)
#pragma unroll
            for (int ni = 0; ni < 4; ++ni)
#pragma unroll
                for (int r = 0; r < 4; ++r)
                    Co[(size_t)(crow0 + mi * 16 + r) * N + ccol0 + ni * 16] =
                            acc[mi][ni][r];
    } else {
        if (bn < 16) {  // K and Q thirds; Q pre-scaled by 0.125*log2(e)
            const float qs = (bn >= 8) ? 0.18033688011112042f : 1.0f;
            u16* Co = (u16*)Cout;
#pragma unroll
            for (int mi = 0; mi < 4; ++mi)
#pragma unroll
                for (int ni = 0; ni < 4; ++ni)
#pragma unroll
                    for (int r = 0; r < 4; ++r)
                        Co[(size_t)(crow0 + mi * 16 + r) * 3072 + ccol0 + ni * 16] =
                                f2bf(acc[mi][ni][r] * qs);
        } else {  // V third -> Vt[(b*1024 + hd)][t]
#pragma unroll
            for (int mi = 0; mi < 4; ++mi) {
                int row = crow0 + mi * 16;
                int bb = row >> 11, t = row & 2047;
#pragma unroll
                for (int ni = 0; ni < 4; ++ni) {
                    int hd = ccol0 + ni * 16 - 2048;
                    uint2 pk;
                    pk.x = pk_bf16(acc[mi][ni][0], acc[mi][ni][1]);
                    pk.y = pk_bf16(acc[mi][ni][2], acc[mi][ni][3]);
                    *(uint2*)&Vt[(size_t)(bb * 1024 + hd) * 2048 + t] = pk;
                }
            }
        }
    }
}

// -------- causal flash attention: swapped QK^T + split-K in block --------
// 512 blocks x 512 threads; block = (bh, pr): passes qt=pr, 31-pr.
// 8 waves = 2 k-parity groups x 4 waves, each group double-buffered K/V.
// P redistribution S^T-frag -> PV-B-frag done ENTIRELY in registers via
// v_permlane32_swap + v_permlane16_swap (no LDS round trip, no lgkm drain):
//   src: lane(lg)=E/O[kbh][h] holds P2=8kb+2lg+h (kb=2kbh+parity)
//   stage1 pl32swap(E,O): reg<->src.b5, lane.b5 = kb-parity
//   stage2 pl16swap(E,O): reg<->src.b4, lane.b4 = src.b5
//   pf_H = {E[H][0], E[H][1], O[H][0], O[H][1]}  (P2 = 16H+4lg+j)
// No-max exp2 softmax (linear -> group partials add); l via ones-MFMA.
__global__ __launch_bounds__(512, 4) void k_attn(
        const u16* __restrict__ kqv, const u16* __restrict__ Vt,
        u16* __restrict__ y) {
    const int orig = blockIdx.x;
    const int xcd = orig & 7, slot = orig >> 3;   // HW: block i -> XCD i%8
    const int bh = xcd * 4 + (slot >> 4);
    const int pr = slot & 15;
    const int b = bh >> 4, h = bh & 15;
    const int tid = threadIdx.x;
    const int wave = tid >> 6;      // 0..7
    const int g = wave >> 2;        // k-parity group
    const int wv4 = wave & 3;
    const int lane = tid & 63;
    const int lg = lane >> 4, lr = lane & 15;

    __shared__ u16 Ks[2][2][64 * 64];  // [group][buf][krow*64+d] swizzled
    __shared__ u16 Vs[2][2][64 * 64];  // [group][buf][d*64+t]    swizzled
    __shared__ u16 comb[4 * 64 * 20];  // combine: 4x uint2 + f32 per entry

    const u16* Kg = kqv + (size_t)b * 2048 * 3072 + h * 64;
    const u16* Qg = Kg + 1024;
    const u16* Vg = Vt + (size_t)bh * 64 * 2048;

    // staging: wave covers rows wv4*16 + (lane>>3) (+8 on 2nd issue);
    // lane's LDS slot = lane&7, so global chunk = slot ^ (row&7)
    const int srow = wv4 * 16 + (lane >> 3);
    const int cK = (lane & 7) ^ (lane >> 3);
    const u16* kg0 = Kg + (size_t)srow * 3072 + cK * 8;
    const u16* vg0 = Vg + (size_t)srow * 2048 + cK * 8;
    const int swz = lr & 7;  // read-side chunk XOR (row&7 == lr&7)

    s16x8 ones;
#pragma unroll
    for (int i = 0; i < 8; ++i) ones[i] = (short)0x3F80;  // bf16 1.0

#define STAGE(bb, t)                                      \
    {                                                     \
        const u16* kp_ = kg0 + (size_t)(t) * 64 * 3072;   \
        const u16* vp_ = vg0 + (size_t)(t) * 64;          \
        u16* lk_ = &Ks[g][bb][wv4 * 1024];                \
        u16* lv_ = &Vs[g][bb][wv4 * 1024];                \
        gload16(kp_, lk_);                                \
        gload16(kp_ + 8 * 3072, lk_ + 512);               \
        gload16(vp_, lv_);                                \
        gload16(vp_ + 8 * 2048, lv_ + 512);               \
    }

    for (int pass = 0; pass < 2; ++pass) {
        const int qt = pass ? (31 - pr) : pr;
        const int nkt = qt + 1;
        const int iters = (nkt + 1) >> 1;   // group0 tile count (>= group1's)
        const int qbase = qt * 64 + wv4 * 16;

        // Q fragments (B-operand: q = lr, d = lg*8..+7), pre-scaled
        const u16* qrp = Qg + (size_t)(qbase + lr) * 3072;
        const s16x8 qf0 = *(const s16x8*)(qrp + lg * 8);
        const s16x8 qf1 = *(const s16x8*)(qrp + 32 + lg * 8);

        f32x4 o[4] = {};  // O^T frags: d = dt*16+lg*4+r, q = lr
        f32x4 l4 = {};    // row-sum (every elem equals the row sum)

        if (g < nkt) STAGE(0, g);
        asm volatile("s_waitcnt vmcnt(0)\n\ts_barrier" ::: "memory");

        for (int i = 0; i < iters; ++i) {
            const int cur = i & 1;
            const int t = 2 * i + g;
            if (t + 2 < nkt) STAGE(cur ^ 1, t + 2);  // flies under compute
            if (t < nkt) {
                // S^T[k][q] = mfma(K,Q); lane: k = kb*16+lg*4+r, q = lr
                f32x4 st[4];
                __builtin_amdgcn_s_setprio(1);
#pragma unroll
                for (int kb = 0; kb < 4; ++kb) {
                    const int row = kb * 16 + lr;
                    s16x8 kf0 = *(const s16x8*)&Ks[g][cur][row * 64 + ((lg ^ swz) << 3)];
                    s16x8 kf1 = *(const s16x8*)&Ks[g][cur][row * 64 + (((4 + lg) ^ swz) << 3)];
                    f32x4 z = {};
                    z = __builtin_amdgcn_mfma_f32_16x16x32_bf16(kf0, qf0, z, 0, 0, 0);
                    z = __builtin_amdgcn_mfma_f32_16x16x32_bf16(kf1, qf1, z, 0, 0, 0);
                    st[kb] = z;
                }
                __builtin_amdgcn_s_setprio(0);

                // p = exp2(st); causal mask only on the diagonal tile
                if (t == nkt - 1) {
                    const int q_abs = qbase + lr;
                    const int kb0 = t * 64 + lg * 4;
#pragma unroll
                    for (int kb = 0; kb < 4; ++kb)
#pragma unroll
                        for (int r = 0; r < 4; ++r)
                            st[kb][r] = EXP2((kb0 + kb * 16 + r <= q_abs)
                                                 ? st[kb][r] : -3e38f);
                } else {
#pragma unroll
                    for (int kb = 0; kb < 4; ++kb)
#pragma unroll
                        for (int r = 0; r < 4; ++r) st[kb][r] = EXP2(st[kb][r]);
                }

                // pack to bf16 pairs + in-register redistribution
                u32 E[2][2], O[2][2];
#pragma unroll
                for (int kbh = 0; kbh < 2; ++kbh)
#pragma unroll
                    for (int hh = 0; hh < 2; ++hh) {
                        E[kbh][hh] = cvtpk(st[2 * kbh][2 * hh], st[2 * kbh][2 * hh + 1]);
                        O[kbh][hh] = cvtpk(st[2 * kbh + 1][2 * hh], st[2 * kbh + 1][2 * hh + 1]);
                    }
#pragma unroll
                for (int kbh = 0; kbh < 2; ++kbh)
#pragma unroll
                    for (int hh = 0; hh < 2; ++hh) {
                        pl32swap(E[kbh][hh], O[kbh][hh]);
                        pl16swap(E[kbh][hh], O[kbh][hh]);
                    }

                // O^T += mfma(V^T, P);  l += mfma(ones, P)
                __builtin_amdgcn_s_setprio(1);
#pragma unroll
                for (int half = 0; half < 2; ++half) {
                    u32x4 pw;
                    pw.x = E[half][0];
                    pw.y = E[half][1];
                    pw.z = O[half][0];
                    pw.w = O[half][1];
                    s16x8 pf = __builtin_bit_cast(s16x8, pw);
                    l4 = __builtin_amdgcn_mfma_f32_16x16x32_bf16(ones, pf, l4, 0, 0, 0);
#pragma unroll
                    for (int dt = 0; dt < 4; ++dt) {
                        const int vrow = dt * 16 + lr;
                        s16x8 vf = *(const s16x8*)&Vs[g][cur][vrow * 64 +
                                                    (((half * 4 + lg) ^ swz) << 3)];
                        o[dt] = __builtin_amdgcn_mfma_f32_16x16x32_bf16(vf, pf, o[dt], 0, 0, 0);
                    }
                }
                __builtin_amdgcn_s_setprio(0);
            }
            // next tile staged & this group's reads of cur done
            asm volatile("s_waitcnt vmcnt(0)\n\ts_barrier" ::: "memory");
        }

        // ---- combine group partials: y = (o0 + o1) / (l0 + l1) ----
        if (g == 1) {
            u16* ce = comb + (size_t)(wv4 * 64 + lane) * 20;
#pragma unroll
            for (int dt = 0; dt < 4; ++dt) {
                uint2 w;
                w.x = cvtpk(o[dt][0], o[dt][1]);
                w.y = cvtpk(o[dt][2], o[dt][3]);
                *(uint2*)(ce + dt * 4) = w;
            }
            *(float*)(ce + 16) = l4[0];
        }
        __syncthreads();
        if (g == 0) {
            const u16* ce = comb + (size_t)(wv4 * 64 + lane) * 20;
            float l = l4[0] + *(const float*)(ce + 16);
#pragma unroll
            for (int dt = 0; dt < 4; ++dt) {
                uint2 w = *(const uint2*)(ce + dt * 4);
                o[dt][0] += bf2f((u16)(w.x & 0xffff));
                o[dt][1] += bf2f((u16)(w.x >> 16));
                o[dt][2] += bf2f((u16)(w.y & 0xffff));
                o[dt][3] += bf2f((u16)(w.y >> 16));
            }
            const float inv = 1.0f / l;
            u16* yb = y + (size_t)(b * 2048 + qbase + lr) * 1024 + h * 64;
#pragma unroll
            for (int dt = 0; dt < 4; ++dt) {
                uint2 w;
                w.x = cvtpk(o[dt][0] * inv, o[dt][1] * inv);
                w.y = cvtpk(o[dt][2] * inv, o[dt][3] * inv);
                *(uint2*)(yb + dt * 16 + lg * 4) = w;
            }
        }
        __syncthreads();  // comb reads done before next pass overwrites
    }
#undef STAGE
}

extern "C" void kernel_launch(void* const* d_in, const int* in_sizes, int n_in,
                              void* d_out, int out_size, void* d_ws, size_t ws_size,
                              hipStream_t stream) {
    const float* x = (const float*)d_in[0];
    const float* w_attn = (const float*)d_in[1];
    const float* w_proj = (const float*)d_in[2];
    float* out = (float*)d_out;
    char* ws = (char*)d_ws;

    u16* x_bf = (u16*)(ws);                        // 8 MB   [4096,1024]
    u16* wat  = (u16*)(ws + (size_t)(8 << 20));    // 6 MB   [3072,1024] = w_attn^T
    u16* wpt  = (u16*)(ws + (size_t)(14 << 20));   // 2 MB   [1024,1024] = w_proj^T
    u16* kqv  = (u16*)(ws + (size_t)(16 << 20));   // 24 MB  [4096,3072] (K,Q thirds)
    u16* vt   = (u16*)(ws + (size_t)(40 << 20));   // 8 MB   [B*H*D, T]
    u16* yb   = (u16*)(ws + (size_t)(48 << 20));   // 8 MB   [4096,1024]

    k_cast<<<4096, 256, 0, stream>>>(x, x_bf);
    k_transpose<<<dim3(96, 32), dim3(32, 8), 0, stream>>>(w_attn, wat, 1024, 3072);
    k_transpose<<<dim3(32, 32), dim3(32, 8), 0, stream>>>(w_proj, wpt, 1024, 1024);
    k_gemm<1><<<32 * 24, 256, 0, stream>>>(x_bf, wat, kqv, vt, 3072, 1024);
    k_attn<<<512, 512, 0, stream>>>(kqv, vt, yb);
    k_gemm<0><<<32 * 8, 256, 0, stream>>>(yb, wpt, out, nullptr, 1024, 1024);
}

// Round 8
// 170.268 us; speedup vs baseline: 1.1846x; 1.0104x over previous
//
#include <hip/hip_runtime.h>

typedef unsigned short u16;
typedef unsigned int u32;

typedef __attribute__((ext_vector_type(4))) float f32x4;
typedef __attribute__((ext_vector_type(8))) short s16x8;
typedef __attribute__((ext_vector_type(4))) u32 u32x4;

__device__ __forceinline__ u16 f2bf(float f) {
    u32 u = __builtin_bit_cast(u32, f);
    u += 0x7fffu + ((u >> 16) & 1u);
    return (u16)(u >> 16);
}

__device__ __forceinline__ u32 pk_bf16(float a, float b) {
    return (u32)f2bf(a) | ((u32)f2bf(b) << 16);
}

// HW packed f32x2 -> bf16x2 (RNE), 1 instr
__device__ __forceinline__ u32 cvtpk(float a, float b) {
    u32 r;
    asm("v_cvt_pk_bf16_f32 %0, %1, %2" : "=v"(r) : "v"(a), "v"(b));
    return r;
}

__device__ __forceinline__ float bf2f(u16 h) {
    u32 u = ((u32)h) << 16;
    return __builtin_bit_cast(float, u);
}

// gfx950 cross-lane swaps (VALU pipe, both operands updated)
__device__ __forceinline__ void pl32swap(u32& a, u32& b) {
    asm volatile("v_permlane32_swap_b32 %0, %1" : "+v"(a), "+v"(b));
}
__device__ __forceinline__ void pl16swap(u32& a, u32& b) {
    asm volatile("v_permlane16_swap_b32 %0, %1" : "+v"(a), "+v"(b));
}

#define EXP2(x) exp2f(x)

// async global -> LDS, 16B per lane; LDS dest = wave-uniform base + lane*16
__device__ __forceinline__ void gload16(const u16* g, u16* l) {
    __builtin_amdgcn_global_load_lds(
        (const __attribute__((address_space(1))) void*)(const void*)g,
        (__attribute__((address_space(3))) void*)(void*)l, 16, 0, 0);
}

// ---- fused prep: cast x (blocks 0..4095), transpose w_attn (next 3072),
// ---- transpose w_proj (last 1024).  256 threads each.
__global__ void k_prep(const float* __restrict__ x, u16* __restrict__ x_bf,
                       const float* __restrict__ wa, u16* __restrict__ wat,
                       const float* __restrict__ wp, u16* __restrict__ wpt) {
    const int bid = blockIdx.x;
    const int tid = threadIdx.x;
    if (bid < 4096) {  // cast: 4 elems/thread
        int i = (bid * 256 + tid) * 4;
        float4 v = *(const float4*)(x + i);
        uint2 pk;
        pk.x = pk_bf16(v.x, v.y);
        pk.y = pk_bf16(v.z, v.w);
        *(uint2*)(x_bf + i) = pk;
        return;
    }
    // transpose+cast: in [K][N] f32 -> out [N][K] bf16
    const float* in;
    u16* out;
    int n0, k0, N;
    if (bid < 4096 + 3072) {
        int loc = bid - 4096;
        in = wa; out = wat; N = 3072;
        n0 = (loc % 96) * 32; k0 = (loc / 96) * 32;
    } else {
        int loc = bid - 4096 - 3072;
        in = wp; out = wpt; N = 1024;
        n0 = (loc & 31) * 32; k0 = (loc >> 5) * 32;
    }
    __shared__ float tile[32][33];
    const int tx = tid & 31, ty = tid >> 5;  // (32,8)
#pragma unroll
    for (int j = 0; j < 32; j += 8)
        tile[ty + j][tx] = in[(size_t)(k0 + ty + j) * N + n0 + tx];
    __syncthreads();
#pragma unroll
    for (int j = 0; j < 32; j += 8)
        out[(size_t)(n0 + ty + j) * 1024 + k0 + tx] = f2bf(tile[tx][ty + j]);
}

// ---------------- GEMM (m97 pattern): C[M,N] = A[M,K] @ Bt[N,K]^T --------
// XCD-bijective block swizzle (nwg % 8 == 0 for both instantiations).
template <int EPI>
__global__ __launch_bounds__(256, 2) void k_gemm(
        const u16* __restrict__ A, const u16* __restrict__ Bt,
        void* __restrict__ Cout, u16* __restrict__ Vt, int N, int K) {
    __shared__ u16 As[128 * 32];
    __shared__ u16 Bs[128 * 32];
    const int nbn = N >> 7;
    const int cpx = (int)gridDim.x >> 3;
    const int bid = (int)blockIdx.x;
    const int swb = (bid & 7) * cpx + (bid >> 3);
    const int bm = swb / nbn, bn = swb % nbn;
    const int tid = threadIdx.x;
    const int wv = tid >> 6, ln = tid & 63;
    const int lg = ln >> 4, lr = ln & 15;
    const int wr = (wv >> 1) << 6, wc = (wv & 1) << 6;

    const u16* gA = A + (size_t)(bm * 128 + wv * 32 + (ln >> 2)) * K + (ln & 3) * 8;
    const u16* gB = Bt + (size_t)(bn * 128 + wv * 32 + (ln >> 2)) * K + (ln & 3) * 8;
    u16* lA = As + wv * 1024;
    u16* lB = Bs + wv * 1024;

    f32x4 acc[4][4] = {};

    for (int k0 = 0; k0 < K; k0 += 32) {
        gload16(gA + k0, lA);
        gload16(gA + k0 + 16 * K, lA + 512);
        gload16(gB + k0, lB);
        gload16(gB + k0 + 16 * K, lB + 512);
        __syncthreads();
        s16x8 af[4], bf[4];
#pragma unroll
        for (int mi = 0; mi < 4; ++mi)
            af[mi] = *(const s16x8*)&As[(wr + mi * 16 + lr) * 32 + lg * 8];
#pragma unroll
        for (int ni = 0; ni < 4; ++ni)
            bf[ni] = *(const s16x8*)&Bs[(wc + ni * 16 + lr) * 32 + lg * 8];
#pragma unroll
        for (int mi = 0; mi < 4; ++mi)
#pragma unroll
            for (int ni = 0; ni < 4; ++ni)
                acc[mi][ni] = __builtin_amdgcn_mfma_f32_16x16x32_bf16(
                        af[mi], bf[ni], acc[mi][ni], 0, 0, 0);
        __syncthreads();
    }

    const int crow0 = bm * 128 + wr + lg * 4;
    const int ccol0 = bn * 128 + wc + lr;
    if (EPI == 0) {
        float* Co = (float*)Cout;
#pragma unroll
        for (int mi = 0; mi < 4; ++mi)
#pragma unroll
            for (int ni = 0; ni < 4; ++ni)
#pragma unroll
                for (int r = 0; r < 4; ++r)
                    Co[(size_t)(crow0 + mi * 16 + r) * N + ccol0 + ni * 16] =
                            acc[mi][ni][r];
    } else {
        if (bn < 16) {  // K and Q thirds; Q pre-scaled by 0.125*log2(e)
            const float qs = (bn >= 8) ? 0.18033688011112042f : 1.0f;
            u16* Co = (u16*)Cout;
#pragma unroll
            for (int mi = 0; mi < 4; ++mi)
#pragma unroll
                for (int ni = 0; ni < 4; ++ni)
#pragma unroll
                    for (int r = 0; r < 4; ++r)
                        Co[(size_t)(crow0 + mi * 16 + r) * 3072 + ccol0 + ni * 16] =
                                f2bf(acc[mi][ni][r] * qs);
        } else {  // V third -> Vt[(b*1024 + hd)][t]
#pragma unroll
            for (int mi = 0; mi < 4; ++mi) {
                int row = crow0 + mi * 16;
                int bb = row >> 11, t = row & 2047;
#pragma unroll
                for (int ni = 0; ni < 4; ++ni) {
                    int hd = ccol0 + ni * 16 - 2048;
                    uint2 pk;
                    pk.x = pk_bf16(acc[mi][ni][0], acc[mi][ni][1]);
                    pk.y = pk_bf16(acc[mi][ni][2], acc[mi][ni][3]);
                    *(uint2*)&Vt[(size_t)(bb * 1024 + hd) * 2048 + t] = pk;
                }
            }
        }
    }
}

// -------- causal flash attention: swapped QK^T + split-K, KVBLK=32 --------
// 512 blocks x 512 threads; block = (bh, pr): passes qt=pr, 31-pr.
// 8 waves = 2 k-parity groups x 4 waves; group g owns 32-key tiles t%2==g,
// each double-buffered (K 32x64, V^T 64x32 per buf).  LDS = 32 KB total
// (combine buffer aliases Vs, dead at combine time) -> 4 blocks/CU,
// 32 waves/CU: barrier/drain windows of one block covered by 3 others.
// P redistribution in regs via permlane32+16 swap; no-max exp2 softmax
// (linear -> group partials add); l via ones-MFMA; Q pre-scaled to log2.
__global__ __launch_bounds__(512, 4) void k_attn(
        const u16* __restrict__ kqv, const u16* __restrict__ Vt,
        u16* __restrict__ y) {
    const int orig = blockIdx.x;
    const int xcd = orig & 7, slot = orig >> 3;   // HW: block i -> XCD i%8
    const int bh = xcd * 4 + (slot >> 4);
    const int pr = slot & 15;
    const int b = bh >> 4, h = bh & 15;
    const int tid = threadIdx.x;
    const int wave = tid >> 6;      // 0..7
    const int g = wave >> 2;        // k-parity group
    const int wv4 = wave & 3;
    const int lane = tid & 63;
    const int lg = lane >> 4, lr = lane & 15;

    __shared__ u16 smem[16384];     // 32 KB total
    // Ks(g,bb): [32 keys][64 d]  at smem + (g*2+bb)*2048
    // Vs(g,bb): [64 d][32 t]     at smem + 8192 + (g*2+bb)*2048
    u16* const KsB = smem;
    u16* const VsB = smem + 8192;
    u16* const comb = VsB;          // aliases Vs; used only after tile loops

    const u16* Kg = kqv + (size_t)b * 2048 * 3072 + h * 64;
    const u16* Qg = Kg + 1024;
    const u16* Vg = Vt + (size_t)bh * 64 * 2048;

    // K staging: wave stages 8 rows; row = wv4*8 + (lane>>3), slot lane&7,
    // global chunk = slot ^ (row&7).
    const u16* kg0 = Kg + (size_t)(wv4 * 8 + (lane >> 3)) * 3072 +
                     (((lane & 7) ^ (lane >> 3)) << 3);
    // V staging: wave stages 16 rows; row = wv4*16 + (lane>>2), slot lane&3,
    // global chunk = slot ^ ((row>>1)&3).
    const u16* vg0 = Vg + (size_t)(wv4 * 16 + (lane >> 2)) * 2048 +
                     (((lane & 3) ^ ((lane >> 3) & 3)) << 3);
    const int swzK = lr & 7;          // K read chunk XOR (row&7 == lr&7)
    const int swzV = (lr >> 1) & 3;   // V read chunk XOR ((vrow>>1)&3)

    s16x8 ones;
#pragma unroll
    for (int i = 0; i < 8; ++i) ones[i] = (short)0x3F80;  // bf16 1.0

#define STAGE(bb, t)                                        \
    {                                                       \
        gload16(kg0 + (size_t)(t) * 32 * 3072,              \
                KsB + (g * 2 + (bb)) * 2048 + wv4 * 512);   \
        gload16(vg0 + (size_t)(t) * 32,                     \
                VsB + (g * 2 + (bb)) * 2048 + wv4 * 512);   \
    }

    for (int pass = 0; pass < 2; ++pass) {
        const int qt = pass ? (31 - pr) : pr;
        const int nkt = 2 * (qt + 1);       // 32-key tiles
        const int iters = qt + 1;           // per group
        const int qbase = qt * 64 + wv4 * 16;

        // Q fragments (B-operand: q = lr, d = lg*8..+7), pre-scaled
        const u16* qrp = Qg + (size_t)(qbase + lr) * 3072;
        const s16x8 qf0 = *(const s16x8*)(qrp + lg * 8);
        const s16x8 qf1 = *(const s16x8*)(qrp + 32 + lg * 8);

        f32x4 o[4] = {};  // O^T frags: d = dt*16+lg*4+r, q = lr
        f32x4 l4 = {};    // row-sum (every elem equals the row sum)

        STAGE(0, g);      // g < nkt always (nkt >= 2)
        asm volatile("s_waitcnt vmcnt(0)\n\ts_barrier" ::: "memory");

        for (int i = 0; i < iters; ++i) {
            const int cur = i & 1;
            const int t = 2 * i + g;
            if (i + 1 < iters) STAGE(cur ^ 1, t + 2);  // flies under compute
            const u16* Kc = KsB + (g * 2 + cur) * 2048;
            const u16* Vc = VsB + (g * 2 + cur) * 2048;

            // S^T[k][q] = mfma(K,Q); lane: k = kb*16+lg*4+r, q = lr
            f32x4 st[2];
            __builtin_amdgcn_s_setprio(1);
#pragma unroll
            for (int kb = 0; kb < 2; ++kb) {
                const int row = kb * 16 + lr;
                s16x8 kf0 = *(const s16x8*)&Kc[row * 64 + ((lg ^ swzK) << 3)];
                s16x8 kf1 = *(const s16x8*)&Kc[row * 64 + (((4 + lg) ^ swzK) << 3)];
                f32x4 z = {};
                z = __builtin_amdgcn_mfma_f32_16x16x32_bf16(kf0, qf0, z, 0, 0, 0);
                z = __builtin_amdgcn_mfma_f32_16x16x32_bf16(kf1, qf1, z, 0, 0, 0);
                st[kb] = z;
            }
            __builtin_amdgcn_s_setprio(0);

            // p = exp2(st); mask on the two boundary tiles only
            if (t >= nkt - 2) {
                const int q_abs = qbase + lr;
                const int kb0 = t * 32 + lg * 4;
#pragma unroll
                for (int kb = 0; kb < 2; ++kb)
#pragma unroll
                    for (int r = 0; r < 4; ++r)
                        st[kb][r] = EXP2((kb0 + kb * 16 + r <= q_abs)
                                             ? st[kb][r] : -3e38f);
            } else {
#pragma unroll
                for (int kb = 0; kb < 2; ++kb)
#pragma unroll
                    for (int r = 0; r < 4; ++r) st[kb][r] = EXP2(st[kb][r]);
            }

            // pack + in-register redistribution (S^T frag -> PV B-frag)
            u32 E[2], O[2];
#pragma unroll
            for (int hh = 0; hh < 2; ++hh) {
                E[hh] = cvtpk(st[0][2 * hh], st[0][2 * hh + 1]);
                O[hh] = cvtpk(st[1][2 * hh], st[1][2 * hh + 1]);
                pl32swap(E[hh], O[hh]);
                pl16swap(E[hh], O[hh]);
            }
            u32x4 pw;
            pw.x = E[0]; pw.y = E[1]; pw.z = O[0]; pw.w = O[1];
            s16x8 pf = __builtin_bit_cast(s16x8, pw);

            // O^T += mfma(V^T, P);  l += mfma(ones, P)
            __builtin_amdgcn_s_setprio(1);
            l4 = __builtin_amdgcn_mfma_f32_16x16x32_bf16(ones, pf, l4, 0, 0, 0);
#pragma unroll
            for (int dt = 0; dt < 4; ++dt) {
                const int vrow = dt * 16 + lr;
                s16x8 vf = *(const s16x8*)&Vc[vrow * 32 + ((lg ^ swzV) << 3)];
                o[dt] = __builtin_amdgcn_mfma_f32_16x16x32_bf16(vf, pf, o[dt], 0, 0, 0);
            }
            __builtin_amdgcn_s_setprio(0);

            // next tile staged & this group's reads of cur done
            asm volatile("s_waitcnt vmcnt(0)\n\ts_barrier" ::: "memory");
        }

        // ---- combine group partials: y = (o0 + o1) / (l0 + l1) ----
        if (g == 1) {
            u16* ce = comb + (size_t)(wv4 * 64 + lane) * 20;
#pragma unroll
            for (int dt = 0; dt < 4; ++dt) {
                uint2 w;
                w.x = cvtpk(o[dt][0], o[dt][1]);
                w.y = cvtpk(o[dt][2], o[dt][3]);
                *(uint2*)(ce + dt * 4) = w;
            }
            *(float*)(ce + 16) = l4[0];
        }
        __syncthreads();
        if (g == 0) {
            const u16* ce = comb + (size_t)(wv4 * 64 + lane) * 20;
            float l = l4[0] + *(const float*)(ce + 16);
#pragma unroll
            for (int dt = 0; dt < 4; ++dt) {
                uint2 w = *(const uint2*)(ce + dt * 4);
                o[dt][0] += bf2f((u16)(w.x & 0xffff));
                o[dt][1] += bf2f((u16)(w.x >> 16));
                o[dt][2] += bf2f((u16)(w.y & 0xffff));
                o[dt][3] += bf2f((u16)(w.y >> 16));
            }
            const float inv = 1.0f / l;
            u16* yb = y + (size_t)(b * 2048 + qbase + lr) * 1024 + h * 64;
#pragma unroll
            for (int dt = 0; dt < 4; ++dt) {
                uint2 w;
                w.x = cvtpk(o[dt][0] * inv, o[dt][1] * inv);
                w.y = cvtpk(o[dt][2] * inv, o[dt][3] * inv);
                *(uint2*)(yb + dt * 16 + lg * 4) = w;
            }
        }
        __syncthreads();  // comb reads done before next pass overwrites
    }
#undef STAGE
}

extern "C" void kernel_launch(void* const* d_in, const int* in_sizes, int n_in,
                              void* d_out, int out_size, void* d_ws, size_t ws_size,
                              hipStream_t stream) {
    const float* x = (const float*)d_in[0];
    const float* w_attn = (const float*)d_in[1];
    const float* w_proj = (const float*)d_in[2];
    float* out = (float*)d_out;
    char* ws = (char*)d_ws;

    u16* x_bf = (u16*)(ws);                        // 8 MB   [4096,1024]
    u16* wat  = (u16*)(ws + (size_t)(8 << 20));    // 6 MB   [3072,1024] = w_attn^T
    u16* wpt  = (u16*)(ws + (size_t)(14 << 20));   // 2 MB   [1024,1024] = w_proj^T
    u16* kqv  = (u16*)(ws + (size_t)(16 << 20));   // 24 MB  [4096,3072] (K,Q thirds)
    u16* vt   = (u16*)(ws + (size_t)(40 << 20));   // 8 MB   [B*H*D, T]
    u16* yb   = (u16*)(ws + (size_t)(48 << 20));   // 8 MB   [4096,1024]

    k_prep<<<4096 + 3072 + 1024, 256, 0, stream>>>(x, x_bf, w_attn, wat,
                                                   w_proj, wpt);
    k_gemm<1><<<32 * 24, 256, 0, stream>>>(x_bf, wat, kqv, vt, 3072, 1024);
    k_attn<<<512, 512, 0, stream>>>(kqv, vt, yb);
    k_gemm<0><<<32 * 8, 256, 0, stream>>>(yb, wpt, out, nullptr, 1024, 1024);
}